// Round 1
// baseline (6476.974 us; speedup 1.0000x reference)
//
#include <hip/hip_runtime.h>
#include <cstdint>
#include <cstddef>

#define HID 64
#define WAVES_PER_BLOCK 4

__device__ __forceinline__ float gelu_exact(float z) {
    // torch/jax exact GELU: 0.5*z*(1+erf(z/sqrt(2)))
    return 0.5f * z * (1.0f + erff(z * 0.70710678118654752f));
}

// One recurrence step for this wave's batch row.
// rb: LDS buffer holding current h (64 floats), read with uniform addresses (broadcast).
// wb: LDS buffer to write new h into.
// wq: lane-private W_s column (64 values as 16 float4, register-resident).
// zbias: b_in[j] + b_s[j] + x_t * W_in[j] already folded.
__device__ __forceinline__ float ssm_step(const float* rb, float* wb,
                                          const float4* wq, float zbias, int lane) {
    const float4* rb4 = reinterpret_cast<const float4*>(rb);
    float4 acc = make_float4(0.f, 0.f, 0.f, 0.f);
#pragma unroll
    for (int i4 = 0; i4 < 16; ++i4) {
        float4 hb = rb4[i4];   // uniform address -> broadcast ds_read_b128
        float4 w  = wq[i4];
        acc.x = fmaf(hb.x, w.x, acc.x);
        acc.y = fmaf(hb.y, w.y, acc.y);
        acc.z = fmaf(hb.z, w.z, acc.z);
        acc.w = fmaf(hb.w, w.w, acc.w);
    }
    float z = (acc.x + acc.y) + (acc.z + acc.w) + zbias;
    float h = gelu_exact(z);
    wb[lane] = h;
    return h;
}

__global__ __launch_bounds__(256, 4)
void ssm_kernel(const float* __restrict__ x,
                const float* __restrict__ W_in,
                const float* __restrict__ b_in,
                const float* __restrict__ W_s,
                const float* __restrict__ b_s,
                const float* __restrict__ W_out,
                const float* __restrict__ b_out,
                float* __restrict__ out,
                int B, int T) {
    __shared__ float hbuf[WAVES_PER_BLOCK][2][HID];

    const int w    = threadIdx.x >> 6;
    const int lane = threadIdx.x & 63;
    const int b    = blockIdx.x * WAVES_PER_BLOCK + w;
    if (b >= B) return;

    // Lane-private weights: lane j holds W_s[:, j] packed by input index i.
    float4 wq[16];
#pragma unroll
    for (int i4 = 0; i4 < 16; ++i4) {
        wq[i4].x = W_s[(4 * i4 + 0) * HID + lane];
        wq[i4].y = W_s[(4 * i4 + 1) * HID + lane];
        wq[i4].z = W_s[(4 * i4 + 2) * HID + lane];
        wq[i4].w = W_s[(4 * i4 + 3) * HID + lane];
    }
    const float win = W_in[lane];
    const float cb  = b_in[lane] + b_s[lane];
    const float wo  = W_out[lane];
    const float bo  = b_out[0];

    float* buf0 = hbuf[w][0];
    float* buf1 = hbuf[w][1];
    buf0[lane] = 0.f;   // h0 = 0; wave-private, no barrier needed

    const size_t xbase = (size_t)b * (size_t)T;
    const int nch = T >> 6;           // T assumed multiple of 64 (8192 here)

    float xv = x[xbase + lane];       // chunk 0, coalesced
    float h  = 0.f;

    for (int tc = 0; tc < nch; ++tc) {
        // prefetch next 64 x values (clamped in-bounds; stale value unused on last chunk)
        int tn = (tc + 1) << 6;
        if (tn >= T) tn = 0;
        float xv_next = x[xbase + (size_t)tn + lane];

#pragma unroll 1
        for (int k = 0; k < 64; k += 2) {
            float x0 = __int_as_float(__builtin_amdgcn_readlane(__float_as_int(xv), k));
            h = ssm_step(buf0, buf1, wq, fmaf(x0, win, cb), lane);
            float x1 = __int_as_float(__builtin_amdgcn_readlane(__float_as_int(xv), k + 1));
            h = ssm_step(buf1, buf0, wq, fmaf(x1, win, cb), lane);
        }
        xv = xv_next;
    }

    // out[b] = sum_j h_j * W_out[j] + b_out
    float v = h * wo;
#pragma unroll
    for (int m = 32; m >= 1; m >>= 1) v += __shfl_xor(v, m, 64);
    if (lane == 0) out[b] = v + bo;
}

extern "C" void kernel_launch(void* const* d_in, const int* in_sizes, int n_in,
                              void* d_out, int out_size, void* d_ws, size_t ws_size,
                              hipStream_t stream) {
    const float* x     = (const float*)d_in[0];
    const float* W_in  = (const float*)d_in[1];
    const float* b_in  = (const float*)d_in[2];
    const float* W_s   = (const float*)d_in[3];
    const float* b_s   = (const float*)d_in[4];
    const float* W_out = (const float*)d_in[5];
    const float* b_out = (const float*)d_in[6];
    float* out = (float*)d_out;

    const int B = out_size;                 // [B,1] output
    const int T = in_sizes[0] / B;          // x is [B,T,1]

    const int blocks = (B + WAVES_PER_BLOCK - 1) / WAVES_PER_BLOCK;
    ssm_kernel<<<blocks, 64 * WAVES_PER_BLOCK, 0, stream>>>(
        x, W_in, b_in, W_s, b_s, W_out, b_out, out, B, T);
}

// Round 2
// 5165.336 us; speedup vs baseline: 1.2539x; 1.2539x over previous
//
#include <hip/hip_runtime.h>
#include <cstdint>
#include <cstddef>

#define HID 64
#define WAVES_PER_BLOCK 4

typedef float v2f __attribute__((ext_vector_type(2)));

// Exact-erf GELU via Abramowitz & Stegun 7.1.26 (max |erf err| ~1.5e-7):
// erf(a) = 1 - t*(a1 + t*(a2 + t*(a3 + t*(a4 + t*a5)))) * exp(-a^2),
// t = 1/(1 + p*a), a >= 0, with odd symmetry.
__device__ __forceinline__ float fast_gelu(float z) {
    float u = z * 0.70710678118654752f;
    float a = __builtin_fabsf(u);
    float d = __builtin_fmaf(0.3275911f, a, 1.0f);
    float t = __fdividef(1.0f, d);          // fast rcp path
    float e = __expf(-a * a);               // native exp (v_exp)
    float p =                   1.061405429f;
    p = __builtin_fmaf(p, t, -1.453152027f);
    p = __builtin_fmaf(p, t,  1.421413741f);
    p = __builtin_fmaf(p, t, -0.284496736f);
    p = __builtin_fmaf(p, t,  0.254829592f);
    p = p * t;
    float er = __builtin_fmaf(-p, e, 1.0f); // erf(|u|)
    er = __builtin_copysignf(er, u);
    return 0.5f * z * (1.0f + er);
}

// One recurrence step. rb: LDS holding current h (uniform-address broadcast
// reads). wb: LDS to write new h. w: 32 register-resident packed W_s column
// pairs (lane j holds W_s[:,j]). zbias = b_in+b_s+x_t*W_in for this lane.
__device__ __forceinline__ float ssm_step(const float* rb, float* wb,
                                          const v2f* w, float zbias, int lane) {
    const float4* rb4 = reinterpret_cast<const float4*>(rb);
    v2f acc0 = {0.f, 0.f}, acc1 = {0.f, 0.f}, acc2 = {0.f, 0.f}, acc3 = {0.f, 0.f};
#pragma unroll
    for (int i4 = 0; i4 < 16; i4 += 2) {
        float4 h0 = rb4[i4];        // broadcast ds_read_b128
        float4 h1 = rb4[i4 + 1];
        v2f ha = {h0.x, h0.y}, hb = {h0.z, h0.w};
        v2f hc = {h1.x, h1.y}, hd = {h1.z, h1.w};
        acc0 = __builtin_elementwise_fma(ha, w[2 * i4 + 0], acc0);  // v_pk_fma_f32
        acc1 = __builtin_elementwise_fma(hb, w[2 * i4 + 1], acc1);
        acc2 = __builtin_elementwise_fma(hc, w[2 * i4 + 2], acc2);
        acc3 = __builtin_elementwise_fma(hd, w[2 * i4 + 3], acc3);
    }
    v2f s = (acc0 + acc1) + (acc2 + acc3);
    float z = s.x + s.y + zbias;
    float h = fast_gelu(z);
    wb[lane] = h;
    return h;
}

__global__ __launch_bounds__(256, 4)
void ssm_kernel(const float* __restrict__ x,
                const float* __restrict__ W_in,
                const float* __restrict__ b_in,
                const float* __restrict__ W_s,
                const float* __restrict__ b_s,
                const float* __restrict__ W_out,
                const float* __restrict__ b_out,
                float* __restrict__ out,
                int B, int T) {
    __shared__ float hbuf[WAVES_PER_BLOCK][2][HID];

    const int w    = threadIdx.x >> 6;
    const int lane = threadIdx.x & 63;
    const int b    = blockIdx.x * WAVES_PER_BLOCK + w;
    if (b >= B) return;

    // Lane-private W_s column, packed as 32 float2 (input pairs i, i+1).
    v2f wq[32];
#pragma unroll
    for (int i2 = 0; i2 < 32; ++i2) {
        wq[i2].x = W_s[(2 * i2 + 0) * HID + lane];
        wq[i2].y = W_s[(2 * i2 + 1) * HID + lane];
    }
    // Pin in VGPRs: defeats load-rematerialization into the inner loop
    // (round-1 VGPR_Count=52 proved the compiler re-loads W_s every step).
#pragma unroll
    for (int i2 = 0; i2 < 32; ++i2) asm volatile("" : "+v"(wq[i2]));

    const float win = W_in[lane];
    const float cb  = b_in[lane] + b_s[lane];
    const float wo  = W_out[lane];
    const float bo  = b_out[0];

    float* buf0 = hbuf[w][0];
    float* buf1 = hbuf[w][1];
    buf0[lane] = 0.f;   // h0 = 0; wave-private, no barrier needed

    const size_t xbase = (size_t)b * (size_t)T;
    const int nch = T >> 6;           // T multiple of 64 (8192 here)

    float xv = x[xbase + lane];       // chunk 0, coalesced (256B/wave)
    float h  = 0.f;

    for (int tc = 0; tc < nch; ++tc) {
        int tn = (tc + 1) << 6;
        if (tn >= T) tn = 0;          // clamped prefetch; stale value unused
        float xv_next = x[xbase + (size_t)tn + lane];

#pragma unroll 1
        for (int k = 0; k < 64; k += 2) {
            float x0 = __int_as_float(__builtin_amdgcn_readlane(__float_as_int(xv), k));
            h = ssm_step(buf0, buf1, wq, __builtin_fmaf(x0, win, cb), lane);
            float x1 = __int_as_float(__builtin_amdgcn_readlane(__float_as_int(xv), k + 1));
            h = ssm_step(buf1, buf0, wq, __builtin_fmaf(x1, win, cb), lane);
        }
        xv = xv_next;
    }

    // out[b] = h . W_out + b_out
    float v = h * wo;
#pragma unroll
    for (int m = 32; m >= 1; m >>= 1) v += __shfl_xor(v, m, 64);
    if (lane == 0) out[b] = v + bo;
}

extern "C" void kernel_launch(void* const* d_in, const int* in_sizes, int n_in,
                              void* d_out, int out_size, void* d_ws, size_t ws_size,
                              hipStream_t stream) {
    const float* x     = (const float*)d_in[0];
    const float* W_in  = (const float*)d_in[1];
    const float* b_in  = (const float*)d_in[2];
    const float* W_s   = (const float*)d_in[3];
    const float* b_s   = (const float*)d_in[4];
    const float* W_out = (const float*)d_in[5];
    const float* b_out = (const float*)d_in[6];
    float* out = (float*)d_out;

    const int B = out_size;                 // [B,1] output
    const int T = in_sizes[0] / B;          // x is [B,T,1]

    const int blocks = (B + WAVES_PER_BLOCK - 1) / WAVES_PER_BLOCK;
    ssm_kernel<<<blocks, 64 * WAVES_PER_BLOCK, 0, stream>>>(
        x, W_in, b_in, W_s, b_s, W_out, b_out, out, B, T);
}

// Round 3
// 4778.426 us; speedup vs baseline: 1.3555x; 1.0810x over previous
//
#include <hip/hip_runtime.h>
#include <cstdint>
#include <cstddef>

#define HID 64
#define WPB 4   // waves per block

// Exact-erf GELU via Abramowitz & Stegun 7.1.26 (max |erf err| ~1.5e-7).
__device__ __forceinline__ float fast_gelu(float z) {
    float u = z * 0.70710678118654752f;
    float a = __builtin_fabsf(u);
    float d = __builtin_fmaf(0.3275911f, a, 1.0f);
    float t = __builtin_amdgcn_rcpf(d);     // v_rcp_f32, 1 instr
    float e = __expf(-a * a);               // v_mul + v_exp
    float p =                   1.061405429f;
    p = __builtin_fmaf(p, t, -1.453152027f);
    p = __builtin_fmaf(p, t,  1.421413741f);
    p = __builtin_fmaf(p, t, -0.284496736f);
    p = __builtin_fmaf(p, t,  0.254829592f);
    p = p * t;
    float er = __builtin_fmaf(-p, e, 1.0f); // erf(|u|)
    er = __builtin_copysignf(er, u);
    return 0.5f * z * (1.0f + er);
}

// 64 weights as NAMED scalar locals (pure SSA -> register-allocatable), pinned.
#define DW4(a,b,c,d) \
    float w##a = W_s[(a)*HID + lane]; float w##b = W_s[(b)*HID + lane]; \
    float w##c = W_s[(c)*HID + lane]; float w##d = W_s[(d)*HID + lane];
#define PW4(a,b,c,d) \
    asm volatile("" : "+v"(w##a)); asm volatile("" : "+v"(w##b)); \
    asm volatile("" : "+v"(w##c)); asm volatile("" : "+v"(w##d));

// One FMA block: broadcast-read 4 h values (one ds_read_b128, uniform addr),
// consume directly into 4 accumulators against register weights.
#define BLK(q, i0, i1, i2, i3) { \
    float4 hv = rb4[q]; \
    a0 = __builtin_fmaf(hv.x, w##i0, a0); \
    a1 = __builtin_fmaf(hv.y, w##i1, a1); \
    a2 = __builtin_fmaf(hv.z, w##i2, a2); \
    a3 = __builtin_fmaf(hv.w, w##i3, a3); }

// One recurrence step: h_new = gelu(W_s^T h + zbias), written to WB.
#define STEP(RB, WB, ZB) { \
    const float4* rb4 = reinterpret_cast<const float4*>(RB); \
    float a0 = 0.f, a1 = 0.f, a2 = 0.f, a3 = 0.f; \
    BLK( 0,  0,  1,  2,  3)  BLK( 1,  4,  5,  6,  7) \
    BLK( 2,  8,  9, 10, 11)  BLK( 3, 12, 13, 14, 15) \
    BLK( 4, 16, 17, 18, 19)  BLK( 5, 20, 21, 22, 23) \
    BLK( 6, 24, 25, 26, 27)  BLK( 7, 28, 29, 30, 31) \
    BLK( 8, 32, 33, 34, 35)  BLK( 9, 36, 37, 38, 39) \
    BLK(10, 40, 41, 42, 43)  BLK(11, 44, 45, 46, 47) \
    BLK(12, 48, 49, 50, 51)  BLK(13, 52, 53, 54, 55) \
    BLK(14, 56, 57, 58, 59)  BLK(15, 60, 61, 62, 63) \
    float z = ((a0 + a1) + (a2 + a3)) + (ZB); \
    h = fast_gelu(z); \
    (WB)[lane] = h; }

__global__ __launch_bounds__(256, 4)
void ssm_kernel(const float* __restrict__ x,
                const float* __restrict__ W_in,
                const float* __restrict__ b_in,
                const float* __restrict__ W_s,
                const float* __restrict__ b_s,
                const float* __restrict__ W_out,
                const float* __restrict__ b_out,
                float* __restrict__ out,
                int B, int T) {
    __shared__ float hbuf[WPB][2][HID];

    const int w    = threadIdx.x >> 6;
    const int lane = threadIdx.x & 63;
    const int b    = blockIdx.x * WPB + w;
    if (b >= B) return;

    // Lane j holds W_s[:, j] as 64 named scalar VGPRs.
    DW4( 0, 1, 2, 3)  DW4( 4, 5, 6, 7)  DW4( 8, 9,10,11)  DW4(12,13,14,15)
    DW4(16,17,18,19)  DW4(20,21,22,23)  DW4(24,25,26,27)  DW4(28,29,30,31)
    DW4(32,33,34,35)  DW4(36,37,38,39)  DW4(40,41,42,43)  DW4(44,45,46,47)
    DW4(48,49,50,51)  DW4(52,53,54,55)  DW4(56,57,58,59)  DW4(60,61,62,63)
    PW4( 0, 1, 2, 3)  PW4( 4, 5, 6, 7)  PW4( 8, 9,10,11)  PW4(12,13,14,15)
    PW4(16,17,18,19)  PW4(20,21,22,23)  PW4(24,25,26,27)  PW4(28,29,30,31)
    PW4(32,33,34,35)  PW4(36,37,38,39)  PW4(40,41,42,43)  PW4(44,45,46,47)
    PW4(48,49,50,51)  PW4(52,53,54,55)  PW4(56,57,58,59)  PW4(60,61,62,63)

    const float win = W_in[lane];
    const float cb  = b_in[lane] + b_s[lane];
    const float wo  = W_out[lane];
    const float bo  = b_out[0];

    float* buf0 = hbuf[w][0];
    float* buf1 = hbuf[w][1];
    buf0[lane] = 0.f;   // h0 = 0; wave-private buffers, no barrier needed

    const size_t xbase = (size_t)b * (size_t)T;
    const int nch = T >> 6;           // T multiple of 64 (8192 here)

    float xv = x[xbase + lane];       // chunk 0, coalesced
    float h  = 0.f;

    for (int tc = 0; tc < nch; ++tc) {
        int tn = (tc + 1) << 6;
        if (tn >= T) tn = 0;          // clamped prefetch; stale value unused
        float xv_next = x[xbase + (size_t)tn + lane];

#pragma unroll 1
        for (int k = 0; k < 64; k += 2) {
            float x0 = __int_as_float(__builtin_amdgcn_readlane(__float_as_int(xv), k));
            STEP(buf0, buf1, __builtin_fmaf(x0, win, cb));
            float x1 = __int_as_float(__builtin_amdgcn_readlane(__float_as_int(xv), k + 1));
            STEP(buf1, buf0, __builtin_fmaf(x1, win, cb));
        }
        xv = xv_next;
    }

    // out[b] = h . W_out + b_out
    float v = h * wo;
#pragma unroll
    for (int m = 32; m >= 1; m >>= 1) v += __shfl_xor(v, m, 64);
    if (lane == 0) out[b] = v + bo;
}

extern "C" void kernel_launch(void* const* d_in, const int* in_sizes, int n_in,
                              void* d_out, int out_size, void* d_ws, size_t ws_size,
                              hipStream_t stream) {
    const float* x     = (const float*)d_in[0];
    const float* W_in  = (const float*)d_in[1];
    const float* b_in  = (const float*)d_in[2];
    const float* W_s   = (const float*)d_in[3];
    const float* b_s   = (const float*)d_in[4];
    const float* W_out = (const float*)d_in[5];
    const float* b_out = (const float*)d_in[6];
    float* out = (float*)d_out;

    const int B = out_size;                 // [B,1] output
    const int T = in_sizes[0] / B;          // x is [B,T,1]

    const int blocks = (B + WPB - 1) / WPB;
    ssm_kernel<<<blocks, 64 * WPB, 0, stream>>>(
        x, W_in, b_in, W_s, b_s, W_out, b_out, out, B, T);
}

// Round 4
// 4613.472 us; speedup vs baseline: 1.4039x; 1.0358x over previous
//
#include <hip/hip_runtime.h>
#include <cstdint>
#include <cstddef>

#define HID 64
#define WPB 4   // waves per block
#define RPW 2   // batch rows per wave

// Exact-erf GELU via Abramowitz & Stegun 7.1.26 (max |erf err| ~1.5e-7).
// ~16 VALU instr: mul, and, fma, rcp, mul, mul, exp, 5x fma, mul, fma, bfi, mul, fma.
__device__ __forceinline__ float fast_gelu(float z) {
    float u = z * 0.70710678118654752f;
    float a = __builtin_fabsf(u);
    float t = __builtin_amdgcn_rcpf(__builtin_fmaf(0.3275911f, a, 1.0f));
    float m = u * u;
    float e = __builtin_amdgcn_exp2f(m * -1.44269504088896f);   // exp(-u^2)
    float p =                   1.061405429f;
    p = __builtin_fmaf(p, t, -1.453152027f);
    p = __builtin_fmaf(p, t,  1.421413741f);
    p = __builtin_fmaf(p, t, -0.284496736f);
    p = __builtin_fmaf(p, t,  0.254829592f);
    p = p * t;
    float er = __builtin_fmaf(-p, e, 1.0f);     // erf(|u|)
    er = __builtin_copysignf(er, u);            // v_bfi_b32
    float zh = 0.5f * z;
    return __builtin_fmaf(zh, er, zh);
}

// 64 weights as named scalar locals, pinned into VGPRs.
#define DW4(a,b,c,d) \
    float w##a = W_s[(a)*HID + lane]; float w##b = W_s[(b)*HID + lane]; \
    float w##c = W_s[(c)*HID + lane]; float w##d = W_s[(d)*HID + lane];
#define PW4(a,b,c,d) \
    asm volatile("" : "+v"(w##a)); asm volatile("" : "+v"(w##b)); \
    asm volatile("" : "+v"(w##c)); asm volatile("" : "+v"(w##d));

// One b128 broadcast feeds BOTH rows: layout {hA[2q], hB[2q], hA[2q+1], hB[2q+1]}.
#define BLK(q, i0, i1) { \
    float4 hv = rb4[q]; \
    aA0 = __builtin_fmaf(hv.x, w##i0, aA0); \
    aB0 = __builtin_fmaf(hv.y, w##i0, aB0); \
    aA1 = __builtin_fmaf(hv.z, w##i1, aA1); \
    aB1 = __builtin_fmaf(hv.w, w##i1, aB1); }

// One 2-row recurrence step: read interleaved h from RB, write to WB.
#define STEP2(RB, WB, XA, XB) { \
    const float4* rb4 = reinterpret_cast<const float4*>(RB); \
    float aA0 = 0.f, aA1 = 0.f, aB0 = 0.f, aB1 = 0.f; \
    BLK( 0,  0,  1)  BLK( 1,  2,  3)  BLK( 2,  4,  5)  BLK( 3,  6,  7) \
    BLK( 4,  8,  9)  BLK( 5, 10, 11)  BLK( 6, 12, 13)  BLK( 7, 14, 15) \
    BLK( 8, 16, 17)  BLK( 9, 18, 19)  BLK(10, 20, 21)  BLK(11, 22, 23) \
    BLK(12, 24, 25)  BLK(13, 26, 27)  BLK(14, 28, 29)  BLK(15, 30, 31) \
    BLK(16, 32, 33)  BLK(17, 34, 35)  BLK(18, 36, 37)  BLK(19, 38, 39) \
    BLK(20, 40, 41)  BLK(21, 42, 43)  BLK(22, 44, 45)  BLK(23, 46, 47) \
    BLK(24, 48, 49)  BLK(25, 50, 51)  BLK(26, 52, 53)  BLK(27, 54, 55) \
    BLK(28, 56, 57)  BLK(29, 58, 59)  BLK(30, 60, 61)  BLK(31, 62, 63) \
    float zA = (aA0 + aA1) + __builtin_fmaf((XA), win, cb); \
    float zB = (aB0 + aB1) + __builtin_fmaf((XB), win, cb); \
    hA = fast_gelu(zA); \
    hB = fast_gelu(zB); \
    float2 st; st.x = hA; st.y = hB; \
    *reinterpret_cast<float2*>((WB) + 2 * lane) = st; }   /* ds_write_b64 */

#define RDL(v, k) __int_as_float(__builtin_amdgcn_readlane(__float_as_int(v), (k)))

__global__ __launch_bounds__(256, 2)
void ssm_kernel(const float* __restrict__ x,
                const float* __restrict__ W_in,
                const float* __restrict__ b_in,
                const float* __restrict__ W_s,
                const float* __restrict__ b_s,
                const float* __restrict__ W_out,
                const float* __restrict__ b_out,
                float* __restrict__ out,
                int B, int T) {
    // [wave][pingpong][interleaved 2*HID]: slot 2j = row A's h[j], 2j+1 = row B's.
    __shared__ float hbuf[WPB][2][2 * HID];

    const int w    = threadIdx.x >> 6;
    const int lane = threadIdx.x & 63;
    const int bA   = (blockIdx.x * WPB + w) * RPW;
    const int bB   = bA + 1;
    if (bA >= B) return;

    // Lane j holds W_s[:, j] as 64 named scalar VGPRs (shared by both rows).
    DW4( 0, 1, 2, 3)  DW4( 4, 5, 6, 7)  DW4( 8, 9,10,11)  DW4(12,13,14,15)
    DW4(16,17,18,19)  DW4(20,21,22,23)  DW4(24,25,26,27)  DW4(28,29,30,31)
    DW4(32,33,34,35)  DW4(36,37,38,39)  DW4(40,41,42,43)  DW4(44,45,46,47)
    DW4(48,49,50,51)  DW4(52,53,54,55)  DW4(56,57,58,59)  DW4(60,61,62,63)
    PW4( 0, 1, 2, 3)  PW4( 4, 5, 6, 7)  PW4( 8, 9,10,11)  PW4(12,13,14,15)
    PW4(16,17,18,19)  PW4(20,21,22,23)  PW4(24,25,26,27)  PW4(28,29,30,31)
    PW4(32,33,34,35)  PW4(36,37,38,39)  PW4(40,41,42,43)  PW4(44,45,46,47)
    PW4(48,49,50,51)  PW4(52,53,54,55)  PW4(56,57,58,59)  PW4(60,61,62,63)

    const float win = W_in[lane];
    const float cb  = b_in[lane] + b_s[lane];
    const float wo  = W_out[lane];
    const float bo  = b_out[0];

    float* buf0 = hbuf[w][0];
    float* buf1 = hbuf[w][1];
    {   // h0 = 0 for both rows; wave-private, no barrier needed
        float2 z2; z2.x = 0.f; z2.y = 0.f;
        *reinterpret_cast<float2*>(buf0 + 2 * lane) = z2;
    }

    const size_t xbaseA = (size_t)bA * (size_t)T;
    const size_t xbaseB = (size_t)bB * (size_t)T;
    const int nch = T >> 6;            // T multiple of 64 (8192 here)

    float xvA = x[xbaseA + lane];      // chunk 0, coalesced (256B per row)
    float xvB = x[xbaseB + lane];
    float hA = 0.f, hB = 0.f;

    for (int tc = 0; tc < nch; ++tc) {
        int tn = (tc + 1) << 6;
        if (tn >= T) tn = 0;           // clamped prefetch; stale value unused
        float xnA = x[xbaseA + (size_t)tn + lane];
        float xnB = x[xbaseB + (size_t)tn + lane];

#pragma unroll 1
        for (int k = 0; k < 64; k += 2) {
            STEP2(buf0, buf1, RDL(xvA, k),     RDL(xvB, k));
            STEP2(buf1, buf0, RDL(xvA, k + 1), RDL(xvB, k + 1));
        }
        xvA = xnA;
        xvB = xnB;
    }

    // out[b] = h . W_out + b_out, both rows reduced in parallel
    float vA = hA * wo;
    float vB = hB * wo;
#pragma unroll
    for (int m = 32; m >= 1; m >>= 1) {
        vA += __shfl_xor(vA, m, 64);
        vB += __shfl_xor(vB, m, 64);
    }
    if (lane == 0) {
        out[bA] = vA + bo;
        out[bB] = vB + bo;
    }
}

extern "C" void kernel_launch(void* const* d_in, const int* in_sizes, int n_in,
                              void* d_out, int out_size, void* d_ws, size_t ws_size,
                              hipStream_t stream) {
    const float* x     = (const float*)d_in[0];
    const float* W_in  = (const float*)d_in[1];
    const float* b_in  = (const float*)d_in[2];
    const float* W_s   = (const float*)d_in[3];
    const float* b_s   = (const float*)d_in[4];
    const float* W_out = (const float*)d_in[5];
    const float* b_out = (const float*)d_in[6];
    float* out = (float*)d_out;

    const int B = out_size;                 // [B,1] output
    const int T = in_sizes[0] / B;          // x is [B,T,1]

    const int rows_per_block = WPB * RPW;   // 8
    const int blocks = (B + rows_per_block - 1) / rows_per_block;   // 512 for B=4096
    ssm_kernel<<<blocks, 64 * WPB, 0, stream>>>(
        x, W_in, b_in, W_s, b_s, W_out, b_out, out, B, T);
}